// Round 1
// baseline (555.952 us; speedup 1.0000x reference)
//
#include <hip/hip_runtime.h>
#include <cstdint>

typedef unsigned short u16;
typedef short s16x8 __attribute__((ext_vector_type(8)));
typedef float f32x4 __attribute__((ext_vector_type(4)));

__device__ __forceinline__ u16 f2bf(float f) {
    union { float f; unsigned int u; } x; x.f = f;
    unsigned int r = (x.u + 0x7FFFu + ((x.u >> 16) & 1u)) >> 16;
    return (u16)r;
}

// ---------------------------------------------------------------------------
// Weight convert: W fp32 [K][N] -> W^T bf16 [N][Kp], zero-padded for k>=K
// ---------------------------------------------------------------------------
__global__ void wt_to_bt(const float* __restrict__ W, u16* __restrict__ WT,
                         int K, int N, int Kp) {
    int idx = blockIdx.x * 256 + threadIdx.x;
    if (idx >= N * Kp) return;
    int n = idx / Kp, k = idx - n * Kp;
    float v = (k < K) ? W[(size_t)k * N + n] : 0.f;
    WT[idx] = f2bf(v);
}

// ---------------------------------------------------------------------------
// LayerNorm over 512, fp32 in -> bf16 out. One wave per row.
// ---------------------------------------------------------------------------
__global__ __launch_bounds__(256)
void ln512(const float* __restrict__ X, const float* __restrict__ g,
           const float* __restrict__ bta, u16* __restrict__ out) {
    const int lane = threadIdx.x & 63, w = threadIdx.x >> 6;
    const long row = (long)blockIdx.x * 4 + w;
    const float* xp = X + row * 512 + lane * 8;
    f32x4 a = *(const f32x4*)xp;
    f32x4 c = *(const f32x4*)(xp + 4);
    float s = 0.f, ss = 0.f;
#pragma unroll
    for (int i = 0; i < 4; i++) { s += a[i] + c[i]; ss += a[i]*a[i] + c[i]*c[i]; }
#pragma unroll
    for (int m = 1; m < 64; m <<= 1) { s += __shfl_xor(s, m); ss += __shfl_xor(ss, m); }
    float mean = s * (1.f / 512.f);
    float var  = ss * (1.f / 512.f) - mean * mean;
    float rs = rsqrtf(var + 1e-5f);
    f32x4 g0 = *(const f32x4*)(g + lane * 8);
    f32x4 g1 = *(const f32x4*)(g + lane * 8 + 4);
    f32x4 b0 = *(const f32x4*)(bta + lane * 8);
    f32x4 b1 = *(const f32x4*)(bta + lane * 8 + 4);
    s16x8 ov;
#pragma unroll
    for (int i = 0; i < 4; i++) {
        ov[i]     = (short)f2bf((a[i] - mean) * rs * g0[i] + b0[i]);
        ov[4 + i] = (short)f2bf((c[i] - mean) * rs * g1[i] + b1[i]);
    }
    *(s16x8*)&out[row * 512 + lane * 8] = ov;
}

// LayerNorm over 100 (Zelta), out padded to 128 cols bf16 (pad = 0)
__global__ __launch_bounds__(256)
void ln_z(const float* __restrict__ Z, const float* __restrict__ g,
          const float* __restrict__ bta, u16* __restrict__ out) {
    const int lane = threadIdx.x & 63, w = threadIdx.x >> 6;
    const long row = (long)blockIdx.x * 4 + w;
    const float* zp = Z + row * 100;
    float x0 = zp[lane];
    float x1 = (lane < 36) ? zp[64 + lane] : 0.f;
    float s = x0 + x1, ss = x0 * x0 + x1 * x1;
#pragma unroll
    for (int m = 1; m < 64; m <<= 1) { s += __shfl_xor(s, m); ss += __shfl_xor(ss, m); }
    float mean = s * 0.01f;
    float var  = ss * 0.01f - mean * mean;
    float rs = rsqrtf(var + 1e-5f);
    out[row * 128 + lane] = f2bf((x0 - mean) * rs * g[lane] + bta[lane]);
    u16 hi = 0;
    if (lane < 36) hi = f2bf((x1 - mean) * rs * g[64 + lane] + bta[64 + lane]);
    out[row * 128 + 64 + lane] = hi;
}

// ---------------------------------------------------------------------------
// GEMM: C[M][N] = A[M][K](bf16) @ B (given as B^T bf16 [N][K])
// EPI 0: out bf16.  EPI 1: out bf16 = gelu(acc + bias).  EPI 2: out fp32 =
// acc (+bias) + res.  128x128 tile, BK=32, 4 waves (2x2 of 64x64).
// ---------------------------------------------------------------------------
template <int EPI>
__global__ __launch_bounds__(256)
void gemm_bt(const u16* __restrict__ A, const u16* __restrict__ BT,
             void* __restrict__ Outv, const float* __restrict__ bias,
             const float* __restrict__ res, int M, int N, int K) {
    __shared__ u16 Ash[128 * 32];
    __shared__ u16 Bsh[128 * 32];
    const int tid = threadIdx.x;
    const int lane = tid & 63, w = tid >> 6;
    const int wm = w >> 1, wn = w & 1;
    const int lr = lane & 15, lg = lane >> 4;
    const long m0 = (long)blockIdx.y * 128, n0 = (long)blockIdx.x * 128;

    f32x4 acc[4][4];
#pragma unroll
    for (int i = 0; i < 4; i++)
#pragma unroll
        for (int j = 0; j < 4; j++) { f32x4 z = {0.f, 0.f, 0.f, 0.f}; acc[i][j] = z; }

    const int aseg = lane & 3;
    const int ksteps = K >> 5;
    for (int kk = 0; kk < ksteps; ++kk) {
        const long k0 = (long)kk * 32;
        __syncthreads();  // previous tile's reads complete
#pragma unroll
        for (int c = 0; c < 2; c++) {
            int ca = w * 2 + c;
            int r = ca * 16 + (lane >> 2);
            __builtin_amdgcn_global_load_lds(
                (const __attribute__((address_space(1))) void*)(A + (m0 + r) * K + k0 + aseg * 8),
                (__attribute__((address_space(3))) void*)(&Ash[ca * 512]), 16, 0, 0);
            __builtin_amdgcn_global_load_lds(
                (const __attribute__((address_space(1))) void*)(BT + (n0 + r) * K + k0 + aseg * 8),
                (__attribute__((address_space(3))) void*)(&Bsh[ca * 512]), 16, 0, 0);
        }
        __syncthreads();  // barrier drains vmcnt -> LDS tile ready
        s16x8 af[4], bf[4];
#pragma unroll
        for (int mi = 0; mi < 4; mi++)
            af[mi] = *(const s16x8*)&Ash[(wm * 64 + mi * 16 + lr) * 32 + lg * 8];
#pragma unroll
        for (int ni = 0; ni < 4; ni++)
            bf[ni] = *(const s16x8*)&Bsh[(wn * 64 + ni * 16 + lr) * 32 + lg * 8];
#pragma unroll
        for (int mi = 0; mi < 4; mi++)
#pragma unroll
            for (int ni = 0; ni < 4; ni++)
                acc[mi][ni] = __builtin_amdgcn_mfma_f32_16x16x32_bf16(af[mi], bf[ni], acc[mi][ni], 0, 0, 0);
    }
    // epilogue: D layout col=lane&15, row=4*(lane>>4)+r  [HW-verified]
#pragma unroll
    for (int mi = 0; mi < 4; mi++) {
#pragma unroll
        for (int ni = 0; ni < 4; ni++) {
#pragma unroll
            for (int r = 0; r < 4; r++) {
                long gm = m0 + wm * 64 + mi * 16 + lg * 4 + r;
                long gn = n0 + wn * 64 + ni * 16 + lr;
                float v = acc[mi][ni][r];
                if constexpr (EPI == 1) {
                    v += bias[gn];
                    v = 0.5f * v * (1.f + erff(v * 0.70710678118654752f));
                }
                if constexpr (EPI == 2) {
                    if (bias) v += bias[gn];
                    v += res[gm * (long)N + gn];
                    ((float*)Outv)[gm * (long)N + gn] = v;
                } else {
                    ((u16*)Outv)[gm * (long)N + gn] = f2bf(v);
                }
            }
        }
    }
}

// ---------------------------------------------------------------------------
// Gated flash attention. 8 heads, d=64, row stride 512 (bf16 Q/K/V/O).
// Block = 4 waves, 64 q-rows (16/wave). BKV=32 per step.
// Swapped QK^T (S^T = K·Q^T) so each lane's softmax row is q = lane&15.
// Gate: numerator masked where s<=0; denominator over all k.
// ---------------------------------------------------------------------------
__global__ __launch_bounds__(256)
void attn_gated(const u16* __restrict__ Q, const u16* __restrict__ Kp,
                const u16* __restrict__ Vp, u16* __restrict__ O,
                int Lq, int Lk) {
    __shared__ u16 Ksh[32 * 72];      // K tile [32][64], rows padded to 72
    __shared__ u16 Vt[64 * 40];       // V^T tile [64][32], rows padded to 40
    __shared__ u16 Psh[4 * 16 * 40];  // per-wave P [16][32], rows padded to 40
    const int tid = threadIdx.x, lane = tid & 63, w = tid >> 6;
    const int lr = lane & 15, lg = lane >> 4;
    const int b = blockIdx.y >> 3, h = blockIdx.y & 7;
    const long qrow0 = (long)b * Lq + (long)blockIdx.x * 64 + w * 16;

    s16x8 qf[2];
    qf[0] = *(const s16x8*)&Q[(qrow0 + lr) * 512 + h * 64 + lg * 8];
    qf[1] = *(const s16x8*)&Q[(qrow0 + lr) * 512 + h * 64 + 32 + lg * 8];

    f32x4 o0[4];
#pragma unroll
    for (int dt = 0; dt < 4; dt++) { f32x4 z = {0.f, 0.f, 0.f, 0.f}; o0[dt] = z; }
    float mrun = -3.0e38f, lrun = 0.f;

    const int trow = tid >> 3, tseg = tid & 7;
    const long kvoff = (long)b * Lk * 512 + h * 64;

    for (int kv0 = 0; kv0 < Lk; kv0 += 32) {
        const long kaddr = kvoff + (long)(kv0 + trow) * 512 + tseg * 8;
        s16x8 kk8 = *(const s16x8*)&Kp[kaddr];
        s16x8 vv8 = *(const s16x8*)&Vp[kaddr];
        *(s16x8*)&Ksh[trow * 72 + tseg * 8] = kk8;
#pragma unroll
        for (int j = 0; j < 8; j++) Vt[(tseg * 8 + j) * 40 + trow] = (u16)vv8[j];
        __syncthreads();

        // S^T: two 16x16 chunks (k-rows), contraction over d=64
        f32x4 st[2];
        { f32x4 z = {0.f, 0.f, 0.f, 0.f}; st[0] = z; st[1] = z; }
#pragma unroll
        for (int c = 0; c < 2; c++)
#pragma unroll
            for (int dc = 0; dc < 2; dc++) {
                s16x8 kf = *(const s16x8*)&Ksh[(c * 16 + lr) * 72 + dc * 32 + lg * 8];
                st[c] = __builtin_amdgcn_mfma_f32_16x16x32_bf16(kf, qf[dc], st[c], 0, 0, 0);
            }
        // lane holds S[q=lr][kv0 + c*16 + 4*lg + r]
        float sv[8];
        float tmax = -3.0e38f;
#pragma unroll
        for (int c = 0; c < 2; c++)
#pragma unroll
            for (int r = 0; r < 4; r++) {
                float x = st[c][r] * 0.125f;
                sv[c * 4 + r] = x;
                tmax = fmaxf(tmax, x);
            }
        tmax = fmaxf(tmax, __shfl_xor(tmax, 16));
        tmax = fmaxf(tmax, __shfl_xor(tmax, 32));
        float mnew = fmaxf(mrun, tmax);
        float psum = 0.f, pm[8];
#pragma unroll
        for (int i = 0; i < 8; i++) {
            float e = __expf(sv[i] - mnew);
            psum += e;
            pm[i] = (sv[i] > 0.f) ? e : 0.f;  // gate on raw-score sign
        }
        psum += __shfl_xor(psum, 16);
        psum += __shfl_xor(psum, 32);
        float fac = __expf(mrun - mnew);
        lrun = lrun * fac + psum;
        mrun = mnew;
        // rescale O accumulators: O rows are q' = 4*lg + r
        float fr0 = __shfl(fac, lg * 4 + 0), fr1 = __shfl(fac, lg * 4 + 1);
        float fr2 = __shfl(fac, lg * 4 + 2), fr3 = __shfl(fac, lg * 4 + 3);
#pragma unroll
        for (int dt = 0; dt < 4; dt++) {
            o0[dt][0] *= fr0; o0[dt][1] *= fr1; o0[dt][2] *= fr2; o0[dt][3] *= fr3;
        }
        // P -> LDS (per-wave region), then PV with sigma-consistent reads
#pragma unroll
        for (int c = 0; c < 2; c++)
#pragma unroll
            for (int r = 0; r < 4; r++)
                Psh[w * 640 + lr * 40 + c * 16 + lg * 4 + r] = f2bf(pm[c * 4 + r]);
        s16x8 pa = *(const s16x8*)&Psh[w * 640 + lr * 40 + lg * 8];
#pragma unroll
        for (int dt = 0; dt < 4; dt++) {
            s16x8 vb = *(const s16x8*)&Vt[(dt * 16 + lr) * 40 + lg * 8];
            o0[dt] = __builtin_amdgcn_mfma_f32_16x16x32_bf16(pa, vb, o0[dt], 0, 0, 0);
        }
        __syncthreads();  // before next K/V restage
    }
    float li0 = 1.f / __shfl(lrun, lg * 4 + 0), li1 = 1.f / __shfl(lrun, lg * 4 + 1);
    float li2 = 1.f / __shfl(lrun, lg * 4 + 2), li3 = 1.f / __shfl(lrun, lg * 4 + 3);
#pragma unroll
    for (int dt = 0; dt < 4; dt++) {
        long ob = qrow0 * 512 + h * 64 + dt * 16 + lr;
        O[ob + (long)(lg * 4 + 0) * 512] = f2bf(o0[dt][0] * li0);
        O[ob + (long)(lg * 4 + 1) * 512] = f2bf(o0[dt][1] * li1);
        O[ob + (long)(lg * 4 + 2) * 512] = f2bf(o0[dt][2] * li2);
        O[ob + (long)(lg * 4 + 3) * 512] = f2bf(o0[dt][3] * li3);
    }
}

// ---------------------------------------------------------------------------
extern "C" void kernel_launch(void* const* d_in, const int* in_sizes, int n_in,
                              void* d_out, int out_size, void* d_ws, size_t ws_size,
                              hipStream_t stream) {
    const float* X    = (const float*)d_in[0];   // [4,2048,512]
    const float* Z    = (const float*)d_in[1];   // [4,1024,100]
    const float* Wq_s = (const float*)d_in[2];
    const float* Wk_s = (const float*)d_in[3];
    const float* Wv_s = (const float*)d_in[4];
    const float* Wo_s = (const float*)d_in[5];
    const float* Wq_c = (const float*)d_in[6];
    const float* Wk_c = (const float*)d_in[7];   // [100,512]
    const float* Wv_c = (const float*)d_in[8];   // [100,512]
    const float* Wo_c = (const float*)d_in[9];
    const float* g1   = (const float*)d_in[10];
    const float* b1   = (const float*)d_in[11];
    const float* g2   = (const float*)d_in[12];
    const float* b2   = (const float*)d_in[13];
    const float* W1   = (const float*)d_in[14];
    const float* bf1  = (const float*)d_in[15];
    const float* W2   = (const float*)d_in[16];
    const float* bf2  = (const float*)d_in[17];
    float* out = (float*)d_out;

    char* p = (char*)d_ws;
    auto take = [&](size_t n) { char* q = p; p += (n + 255) & ~(size_t)255; return q; };
    u16* WqsT = (u16*)take(512 * 512 * 2);
    u16* WksT = (u16*)take(512 * 512 * 2);
    u16* WvsT = (u16*)take(512 * 512 * 2);
    u16* WosT = (u16*)take(512 * 512 * 2);
    u16* WqcT = (u16*)take(512 * 512 * 2);
    u16* WocT = (u16*)take(512 * 512 * 2);
    u16* W1T  = (u16*)take(512 * 512 * 2);
    u16* W2T  = (u16*)take(512 * 512 * 2);
    u16* WkcT = (u16*)take(512 * 128 * 2);
    u16* WvcT = (u16*)take(512 * 128 * 2);
    u16* nbuf = (u16*)take((size_t)8192 * 512 * 2);
    u16* qbuf = (u16*)take((size_t)8192 * 512 * 2);
    u16* kbuf = (u16*)take((size_t)8192 * 512 * 2);
    u16* vbuf = (u16*)take((size_t)8192 * 512 * 2);
    u16* abuf = (u16*)take((size_t)8192 * 512 * 2);
    u16* znb  = (u16*)take((size_t)4096 * 128 * 2);

    // weights -> bf16 transposed
    wt_to_bt<<<1024, 256, 0, stream>>>(Wq_s, WqsT, 512, 512, 512);
    wt_to_bt<<<1024, 256, 0, stream>>>(Wk_s, WksT, 512, 512, 512);
    wt_to_bt<<<1024, 256, 0, stream>>>(Wv_s, WvsT, 512, 512, 512);
    wt_to_bt<<<1024, 256, 0, stream>>>(Wo_s, WosT, 512, 512, 512);
    wt_to_bt<<<1024, 256, 0, stream>>>(Wq_c, WqcT, 512, 512, 512);
    wt_to_bt<<<1024, 256, 0, stream>>>(Wo_c, WocT, 512, 512, 512);
    wt_to_bt<<<1024, 256, 0, stream>>>(W1,   W1T,  512, 512, 512);
    wt_to_bt<<<1024, 256, 0, stream>>>(W2,   W2T,  512, 512, 512);
    wt_to_bt<<<256, 256, 0, stream>>>(Wk_c, WkcT, 100, 512, 128);
    wt_to_bt<<<256, 256, 0, stream>>>(Wv_c, WvcT, 100, 512, 128);

    // stage 1: self attention
    ln512<<<2048, 256, 0, stream>>>(X, g1, b1, nbuf);
    gemm_bt<0><<<dim3(4, 64), 256, 0, stream>>>(nbuf, WqsT, qbuf, nullptr, nullptr, 8192, 512, 512);
    gemm_bt<0><<<dim3(4, 64), 256, 0, stream>>>(nbuf, WksT, kbuf, nullptr, nullptr, 8192, 512, 512);
    gemm_bt<0><<<dim3(4, 64), 256, 0, stream>>>(nbuf, WvsT, vbuf, nullptr, nullptr, 8192, 512, 512);
    attn_gated<<<dim3(32, 32), 256, 0, stream>>>(qbuf, kbuf, vbuf, abuf, 2048, 2048);
    gemm_bt<2><<<dim3(4, 64), 256, 0, stream>>>(abuf, WosT, d_out, nullptr, X, 8192, 512, 512);  // X1 -> d_out

    // stage 2: cross attention
    ln512<<<2048, 256, 0, stream>>>(out, g1, b1, nbuf);
    ln_z<<<1024, 256, 0, stream>>>(Z, g2, b2, znb);
    gemm_bt<0><<<dim3(4, 64), 256, 0, stream>>>(nbuf, WqcT, qbuf, nullptr, nullptr, 8192, 512, 512);
    gemm_bt<0><<<dim3(4, 32), 256, 0, stream>>>(znb, WkcT, kbuf, nullptr, nullptr, 4096, 512, 128);
    gemm_bt<0><<<dim3(4, 32), 256, 0, stream>>>(znb, WvcT, vbuf, nullptr, nullptr, 4096, 512, 128);
    attn_gated<<<dim3(32, 32), 256, 0, stream>>>(qbuf, kbuf, vbuf, abuf, 2048, 1024);
    gemm_bt<2><<<dim3(4, 64), 256, 0, stream>>>(abuf, WocT, d_out, nullptr, out, 8192, 512, 512);  // X2 -> d_out (in-place res)

    // stage 3: FFN
    ln512<<<2048, 256, 0, stream>>>(out, g1, b1, nbuf);
    gemm_bt<1><<<dim3(4, 64), 256, 0, stream>>>(nbuf, W1T, abuf, bf1, nullptr, 8192, 512, 512);
    gemm_bt<2><<<dim3(4, 64), 256, 0, stream>>>(abuf, W2T, d_out, bf2, out, 8192, 512, 512);  // X3 -> d_out
}

// Round 3
// 502.752 us; speedup vs baseline: 1.1058x; 1.1058x over previous
//
#include <hip/hip_runtime.h>
#include <cstdint>

typedef unsigned short u16;
typedef short s16x8 __attribute__((ext_vector_type(8)));
typedef float f32x4 __attribute__((ext_vector_type(4)));

__device__ __forceinline__ u16 f2bf(float f) {
    union { float f; unsigned int u; } x; x.f = f;
    unsigned int r = (x.u + 0x7FFFu + ((x.u >> 16) & 1u)) >> 16;
    return (u16)r;
}

// ---------------------------------------------------------------------------
// Batched weight convert: W fp32 [K][N] -> W^T bf16 [N][Kp], zero pad k>=K.
// blockIdx.y selects which weight.
// ---------------------------------------------------------------------------
struct WPtrs { const float* s[8]; u16* d[8]; };

__global__ void wt_batch(WPtrs p, int K, int N, int Kp) {
    int idx = blockIdx.x * 256 + threadIdx.x;
    if (idx >= N * Kp) return;
    int n = idx / Kp, k = idx - n * Kp;
    const float* W = p.s[blockIdx.y];
    float v = (k < K) ? W[(size_t)k * N + n] : 0.f;
    p.d[blockIdx.y][idx] = f2bf(v);
}

// ---------------------------------------------------------------------------
// LayerNorm over 512, fp32 in -> bf16 out. One wave per row.
// ---------------------------------------------------------------------------
__global__ __launch_bounds__(256)
void ln512(const float* __restrict__ X, const float* __restrict__ g,
           const float* __restrict__ bta, u16* __restrict__ out) {
    const int lane = threadIdx.x & 63, w = threadIdx.x >> 6;
    const long row = (long)blockIdx.x * 4 + w;
    const float* xp = X + row * 512 + lane * 8;
    f32x4 a = *(const f32x4*)xp;
    f32x4 c = *(const f32x4*)(xp + 4);
    float s = 0.f, ss = 0.f;
#pragma unroll
    for (int i = 0; i < 4; i++) { s += a[i] + c[i]; ss += a[i]*a[i] + c[i]*c[i]; }
#pragma unroll
    for (int m = 1; m < 64; m <<= 1) { s += __shfl_xor(s, m); ss += __shfl_xor(ss, m); }
    float mean = s * (1.f / 512.f);
    float var  = ss * (1.f / 512.f) - mean * mean;
    float rs = rsqrtf(var + 1e-5f);
    f32x4 g0 = *(const f32x4*)(g + lane * 8);
    f32x4 g1 = *(const f32x4*)(g + lane * 8 + 4);
    f32x4 b0 = *(const f32x4*)(bta + lane * 8);
    f32x4 b1 = *(const f32x4*)(bta + lane * 8 + 4);
    s16x8 ov;
#pragma unroll
    for (int i = 0; i < 4; i++) {
        ov[i]     = (short)f2bf((a[i] - mean) * rs * g0[i] + b0[i]);
        ov[4 + i] = (short)f2bf((c[i] - mean) * rs * g1[i] + b1[i]);
    }
    *(s16x8*)&out[row * 512 + lane * 8] = ov;
}

// LayerNorm over 100 (Zelta), out padded to 128 cols bf16 (pad = 0)
__global__ __launch_bounds__(256)
void ln_z(const float* __restrict__ Z, const float* __restrict__ g,
          const float* __restrict__ bta, u16* __restrict__ out) {
    const int lane = threadIdx.x & 63, w = threadIdx.x >> 6;
    const long row = (long)blockIdx.x * 4 + w;
    const float* zp = Z + row * 100;
    float x0 = zp[lane];
    float x1 = (lane < 36) ? zp[64 + lane] : 0.f;
    float s = x0 + x1, ss = x0 * x0 + x1 * x1;
#pragma unroll
    for (int m = 1; m < 64; m <<= 1) { s += __shfl_xor(s, m); ss += __shfl_xor(ss, m); }
    float mean = s * 0.01f;
    float var  = ss * 0.01f - mean * mean;
    float rs = rsqrtf(var + 1e-5f);
    out[row * 128 + lane] = f2bf((x0 - mean) * rs * g[lane] + bta[lane]);
    u16 hi = 0;
    if (lane < 36) hi = f2bf((x1 - mean) * rs * g[64 + lane] + bta[64 + lane]);
    out[row * 128 + 64 + lane] = hi;
}

// ---------------------------------------------------------------------------
// GEMM: C[M][N] = A[M][K](bf16) @ B (given as B^T bf16 [N][K])
// EPI 0: out bf16.  EPI 1: out bf16 = gelu(acc + bias).  EPI 2: out fp32 =
// acc (+bias) + res.  128x128 tile, BK=32, 4 waves (2x2 of 64x64).
// ---------------------------------------------------------------------------
template <int EPI>
__global__ __launch_bounds__(256)
void gemm_bt(const u16* __restrict__ A, const u16* __restrict__ BT,
             void* __restrict__ Outv, const float* __restrict__ bias,
             const float* __restrict__ res, int M, int N, int K) {
    __shared__ u16 Ash[128 * 32];
    __shared__ u16 Bsh[128 * 32];
    const int tid = threadIdx.x;
    const int lane = tid & 63, w = tid >> 6;
    const int wm = w >> 1, wn = w & 1;
    const int lr = lane & 15, lg = lane >> 4;
    const long m0 = (long)blockIdx.y * 128, n0 = (long)blockIdx.x * 128;

    f32x4 acc[4][4];
#pragma unroll
    for (int i = 0; i < 4; i++)
#pragma unroll
        for (int j = 0; j < 4; j++) { f32x4 z = {0.f, 0.f, 0.f, 0.f}; acc[i][j] = z; }

    const int aseg = lane & 3;
    const int ksteps = K >> 5;
    for (int kk = 0; kk < ksteps; ++kk) {
        const long k0 = (long)kk * 32;
        __syncthreads();  // previous tile's reads complete
#pragma unroll
        for (int c = 0; c < 2; c++) {
            int ca = w * 2 + c;
            int r = ca * 16 + (lane >> 2);
            __builtin_amdgcn_global_load_lds(
                (const __attribute__((address_space(1))) void*)(A + (m0 + r) * K + k0 + aseg * 8),
                (__attribute__((address_space(3))) void*)(&Ash[ca * 512]), 16, 0, 0);
            __builtin_amdgcn_global_load_lds(
                (const __attribute__((address_space(1))) void*)(BT + (n0 + r) * K + k0 + aseg * 8),
                (__attribute__((address_space(3))) void*)(&Bsh[ca * 512]), 16, 0, 0);
        }
        __syncthreads();  // barrier drains vmcnt -> LDS tile ready
        s16x8 af[4], bf[4];
#pragma unroll
        for (int mi = 0; mi < 4; mi++)
            af[mi] = *(const s16x8*)&Ash[(wm * 64 + mi * 16 + lr) * 32 + lg * 8];
#pragma unroll
        for (int ni = 0; ni < 4; ni++)
            bf[ni] = *(const s16x8*)&Bsh[(wn * 64 + ni * 16 + lr) * 32 + lg * 8];
#pragma unroll
        for (int mi = 0; mi < 4; mi++)
#pragma unroll
            for (int ni = 0; ni < 4; ni++)
                acc[mi][ni] = __builtin_amdgcn_mfma_f32_16x16x32_bf16(af[mi], bf[ni], acc[mi][ni], 0, 0, 0);
    }
    // epilogue: D layout: m = 4*(lane>>4)+reg, n = lane&15 (verified in r1)
#pragma unroll
    for (int mi = 0; mi < 4; mi++) {
#pragma unroll
        for (int ni = 0; ni < 4; ni++) {
#pragma unroll
            for (int r = 0; r < 4; r++) {
                long gm = m0 + wm * 64 + mi * 16 + lg * 4 + r;
                long gn = n0 + wn * 64 + ni * 16 + lr;
                float v = acc[mi][ni][r];
                if constexpr (EPI == 1) {
                    v += bias[gn];
                    v = 0.5f * v * (1.f + erff(v * 0.70710678118654752f));
                }
                if constexpr (EPI == 2) {
                    if (bias) v += bias[gn];
                    v += res[gm * (long)N + gn];
                    ((float*)Outv)[gm * (long)N + gn] = v;
                } else {
                    ((u16*)Outv)[gm * (long)N + gn] = f2bf(v);
                }
            }
        }
    }
}

// ---------------------------------------------------------------------------
// Gated flash attention v2. 8 heads, d=64. Q/K row-major [tokens][512];
// V pre-transposed: VT [512 dims][Tk tokens]. No K/V LDS staging, no
// barriers: all fragments are direct 16B global loads (L2-resident).
// Block = 4 waves; each wave owns 32 q-rows (2 subtiles of 16). BKV=32.
// Swapped QK^T (S^T = K*Q^T) -> softmax rows are lane-local (q = lane&15).
// Gate: numerator masked where s<=0; denominator over all k.
// ---------------------------------------------------------------------------
__global__ __launch_bounds__(256)
void attn_gated2(const u16* __restrict__ Q, const u16* __restrict__ Kp,
                 const u16* __restrict__ VT, u16* __restrict__ O,
                 int Lq, int Lk, int Tk) {
    __shared__ u16 Psh[4][2][16 * 40];  // per-wave, per-subtile P bounce
    const int tid = threadIdx.x, lane = tid & 63, w = tid >> 6;
    const int lr = lane & 15, lg = lane >> 4;
    const int b = blockIdx.y >> 3, h = blockIdx.y & 7;
    const long qrow0 = (long)b * Lq + (long)blockIdx.x * 128 + w * 32;
    const long kbase = (long)b * Lk;
    const int hoff = h * 64;

    s16x8 qf[2][2];
#pragma unroll
    for (int s = 0; s < 2; s++)
#pragma unroll
        for (int dc = 0; dc < 2; dc++)
            qf[s][dc] = *(const s16x8*)&Q[(qrow0 + s * 16 + lr) * 512 + hoff + dc * 32 + lg * 8];

    f32x4 o[2][4];
#pragma unroll
    for (int s = 0; s < 2; s++)
#pragma unroll
        for (int dt = 0; dt < 4; dt++) { f32x4 z = {0.f, 0.f, 0.f, 0.f}; o[s][dt] = z; }
    float mrun[2] = {-3.0e38f, -3.0e38f}, lrun[2] = {0.f, 0.f};

    for (int kv0 = 0; kv0 < Lk; kv0 += 32) {
        s16x8 kf[2][2], vb[4];
#pragma unroll
        for (int c = 0; c < 2; c++)
#pragma unroll
            for (int dc = 0; dc < 2; dc++)
                kf[c][dc] = *(const s16x8*)&Kp[(kbase + kv0 + c * 16 + lr) * 512 + hoff + dc * 32 + lg * 8];
#pragma unroll
        for (int dt = 0; dt < 4; dt++)
            vb[dt] = *(const s16x8*)&VT[(long)(hoff + dt * 16 + lr) * Tk + kbase + kv0 + lg * 8];

#pragma unroll
        for (int s = 0; s < 2; s++) {
            f32x4 st[2];
            { f32x4 z = {0.f, 0.f, 0.f, 0.f}; st[0] = z; st[1] = z; }
#pragma unroll
            for (int c = 0; c < 2; c++)
#pragma unroll
                for (int dc = 0; dc < 2; dc++)
                    st[c] = __builtin_amdgcn_mfma_f32_16x16x32_bf16(kf[c][dc], qf[s][dc], st[c], 0, 0, 0);
            // lane holds S[k = kv0 + c*16 + 4*lg + r][q = lr]
            float sv[8], tmax = -3.0e38f;
#pragma unroll
            for (int c = 0; c < 2; c++)
#pragma unroll
                for (int r = 0; r < 4; r++) {
                    float x = st[c][r] * 0.125f;
                    sv[c * 4 + r] = x;
                    tmax = fmaxf(tmax, x);
                }
            tmax = fmaxf(tmax, __shfl_xor(tmax, 16));
            tmax = fmaxf(tmax, __shfl_xor(tmax, 32));
            float mnew = fmaxf(mrun[s], tmax);
            float psum = 0.f, pm[8];
#pragma unroll
            for (int i = 0; i < 8; i++) {
                float e = __expf(sv[i] - mnew);
                psum += e;
                pm[i] = (sv[i] > 0.f) ? e : 0.f;  // gate on raw-score sign
            }
            psum += __shfl_xor(psum, 16);
            psum += __shfl_xor(psum, 32);
            float fac = __expf(mrun[s] - mnew);
            lrun[s] = lrun[s] * fac + psum;
            mrun[s] = mnew;
            float fr0 = __shfl(fac, lg * 4 + 0), fr1 = __shfl(fac, lg * 4 + 1);
            float fr2 = __shfl(fac, lg * 4 + 2), fr3 = __shfl(fac, lg * 4 + 3);
#pragma unroll
            for (int dt = 0; dt < 4; dt++) {
                o[s][dt][0] *= fr0; o[s][dt][1] *= fr1;
                o[s][dt][2] *= fr2; o[s][dt][3] *= fr3;
            }
            // P -> wave-private LDS bounce (no barrier needed)
            u16* psh = &Psh[w][s][0];
#pragma unroll
            for (int c = 0; c < 2; c++)
#pragma unroll
                for (int r = 0; r < 4; r++)
                    psh[lr * 40 + c * 16 + lg * 4 + r] = f2bf(pm[c * 4 + r]);
            s16x8 pa = *(const s16x8*)&psh[lr * 40 + lg * 8];
#pragma unroll
            for (int dt = 0; dt < 4; dt++)
                o[s][dt] = __builtin_amdgcn_mfma_f32_16x16x32_bf16(pa, vb[dt], o[s][dt], 0, 0, 0);
        }
    }
#pragma unroll
    for (int s = 0; s < 2; s++) {
        float li0 = 1.f / __shfl(lrun[s], lg * 4 + 0), li1 = 1.f / __shfl(lrun[s], lg * 4 + 1);
        float li2 = 1.f / __shfl(lrun[s], lg * 4 + 2), li3 = 1.f / __shfl(lrun[s], lg * 4 + 3);
#pragma unroll
        for (int dt = 0; dt < 4; dt++) {
            long ob = (qrow0 + s * 16) * 512 + hoff + dt * 16 + lr;
            O[ob + (long)(lg * 4 + 0) * 512] = f2bf(o[s][dt][0] * li0);
            O[ob + (long)(lg * 4 + 1) * 512] = f2bf(o[s][dt][1] * li1);
            O[ob + (long)(lg * 4 + 2) * 512] = f2bf(o[s][dt][2] * li2);
            O[ob + (long)(lg * 4 + 3) * 512] = f2bf(o[s][dt][3] * li3);
        }
    }
}

// ---------------------------------------------------------------------------
extern "C" void kernel_launch(void* const* d_in, const int* in_sizes, int n_in,
                              void* d_out, int out_size, void* d_ws, size_t ws_size,
                              hipStream_t stream) {
    const float* X    = (const float*)d_in[0];   // [4,2048,512]
    const float* Z    = (const float*)d_in[1];   // [4,1024,100]
    const float* Wq_s = (const float*)d_in[2];
    const float* Wk_s = (const float*)d_in[3];
    const float* Wv_s = (const float*)d_in[4];
    const float* Wo_s = (const float*)d_in[5];
    const float* Wq_c = (const float*)d_in[6];
    const float* Wk_c = (const float*)d_in[7];   // [100,512]
    const float* Wv_c = (const float*)d_in[8];   // [100,512]
    const float* Wo_c = (const float*)d_in[9];
    const float* g1   = (const float*)d_in[10];
    const float* b1   = (const float*)d_in[11];
    const float* g2   = (const float*)d_in[12];
    const float* b2   = (const float*)d_in[13];
    const float* W1   = (const float*)d_in[14];
    const float* bf1  = (const float*)d_in[15];
    const float* W2   = (const float*)d_in[16];
    const float* bf2  = (const float*)d_in[17];
    float* out = (float*)d_out;

    char* p = (char*)d_ws;
    auto take = [&](size_t n) { char* q = p; p += (n + 255) & ~(size_t)255; return q; };
    u16* WqsT = (u16*)take(512 * 512 * 2);
    u16* WksT = (u16*)take(512 * 512 * 2);
    u16* WvsT = (u16*)take(512 * 512 * 2);
    u16* WosT = (u16*)take(512 * 512 * 2);
    u16* WqcT = (u16*)take(512 * 512 * 2);
    u16* WocT = (u16*)take(512 * 512 * 2);
    u16* W1T  = (u16*)take(512 * 512 * 2);
    u16* W2T  = (u16*)take(512 * 512 * 2);
    u16* WkcT = (u16*)take(512 * 128 * 2);
    u16* WvcT = (u16*)take(512 * 128 * 2);
    u16* nbuf = (u16*)take((size_t)8192 * 512 * 2);
    u16* qbuf = (u16*)take((size_t)8192 * 512 * 2);
    u16* kbuf = (u16*)take((size_t)8192 * 512 * 2);
    u16* vtbuf = (u16*)take((size_t)8192 * 512 * 2);  // V^T [512][tokens]
    u16* abuf = (u16*)take((size_t)8192 * 512 * 2);
    u16* znb  = (u16*)take((size_t)4096 * 128 * 2);

    // weights -> bf16 transposed (2 batched launches)
    WPtrs w8{};
    w8.s[0] = Wq_s; w8.d[0] = WqsT;
    w8.s[1] = Wk_s; w8.d[1] = WksT;
    w8.s[2] = Wv_s; w8.d[2] = WvsT;
    w8.s[3] = Wo_s; w8.d[3] = WosT;
    w8.s[4] = Wq_c; w8.d[4] = WqcT;
    w8.s[5] = Wo_c; w8.d[5] = WocT;
    w8.s[6] = W1;   w8.d[6] = W1T;
    w8.s[7] = W2;   w8.d[7] = W2T;
    wt_batch<<<dim3(1024, 8), 256, 0, stream>>>(w8, 512, 512, 512);
    WPtrs w2{};
    w2.s[0] = Wk_c; w2.d[0] = WkcT;
    w2.s[1] = Wv_c; w2.d[1] = WvcT;
    wt_batch<<<dim3(256, 2), 256, 0, stream>>>(w2, 100, 512, 128);

    // stage 1: self attention
    ln512<<<2048, 256, 0, stream>>>(X, g1, b1, nbuf);
    gemm_bt<0><<<dim3(4, 64), 256, 0, stream>>>(nbuf, WqsT, qbuf, nullptr, nullptr, 8192, 512, 512);
    gemm_bt<0><<<dim3(4, 64), 256, 0, stream>>>(nbuf, WksT, kbuf, nullptr, nullptr, 8192, 512, 512);
    // V transposed for free: vtbuf[n][m] = sum_k WvsT[n][k] * nbuf[m][k]
    gemm_bt<0><<<dim3(64, 4), 256, 0, stream>>>(WvsT, nbuf, vtbuf, nullptr, nullptr, 512, 8192, 512);
    attn_gated2<<<dim3(16, 32), 256, 0, stream>>>(qbuf, kbuf, vtbuf, abuf, 2048, 2048, 8192);
    gemm_bt<2><<<dim3(4, 64), 256, 0, stream>>>(abuf, WosT, d_out, nullptr, X, 8192, 512, 512);

    // stage 2: cross attention
    ln512<<<2048, 256, 0, stream>>>(out, g1, b1, nbuf);
    ln_z<<<1024, 256, 0, stream>>>(Z, g2, b2, znb);
    gemm_bt<0><<<dim3(4, 64), 256, 0, stream>>>(nbuf, WqcT, qbuf, nullptr, nullptr, 8192, 512, 512);
    gemm_bt<0><<<dim3(4, 32), 256, 0, stream>>>(znb, WkcT, kbuf, nullptr, nullptr, 4096, 512, 128);
    gemm_bt<0><<<dim3(32, 4), 256, 0, stream>>>(WvcT, znb, vtbuf, nullptr, nullptr, 512, 4096, 128);
    attn_gated2<<<dim3(16, 32), 256, 0, stream>>>(qbuf, kbuf, vtbuf, abuf, 2048, 1024, 4096);
    gemm_bt<2><<<dim3(4, 64), 256, 0, stream>>>(abuf, WocT, d_out, nullptr, out, 8192, 512, 512);

    // stage 3: FFN
    ln512<<<2048, 256, 0, stream>>>(out, g1, b1, nbuf);
    gemm_bt<1><<<dim3(4, 64), 256, 0, stream>>>(nbuf, W1T, abuf, bf1, nullptr, 8192, 512, 512);
    gemm_bt<2><<<dim3(4, 64), 256, 0, stream>>>(abuf, W2T, d_out, bf2, out, 8192, 512, 512);
}

// Round 5
// 476.304 us; speedup vs baseline: 1.1672x; 1.0555x over previous
//
#include <hip/hip_runtime.h>
#include <hip/hip_bf16.h>
#include <cstdint>

typedef unsigned short u16;
typedef short s16x8 __attribute__((ext_vector_type(8)));
typedef float f32x4 __attribute__((ext_vector_type(4)));

// 0.125 (1/sqrt(64)) * log2(e): folded into Q so QK^T yields s*log2e for exp2
#define QSCALE 0.18033688011112042f

__device__ __forceinline__ u16 f2bf(float f) {
    union { float f; unsigned int u; } x; x.f = f;
    unsigned int r = (x.u + 0x7FFFu + ((x.u >> 16) & 1u)) >> 16;
    return (u16)r;
}

__device__ __forceinline__ unsigned pack_bf2(float a, float b) {
    return (unsigned)f2bf(a) | ((unsigned)f2bf(b) << 16);
}

// ---------------------------------------------------------------------------
// Batched weight convert: W fp32 [K][N] -> W^T bf16 [N][Kp], zero pad k>=K.
// ---------------------------------------------------------------------------
struct WPtrs { const float* s[8]; u16* d[8]; };

__global__ void wt_batch(WPtrs p, int K, int N, int Kp) {
    int idx = blockIdx.x * 256 + threadIdx.x;
    if (idx >= N * Kp) return;
    int n = idx / Kp, k = idx - n * Kp;
    const float* W = p.s[blockIdx.y];
    float v = (k < K) ? W[(size_t)k * N + n] : 0.f;
    p.d[blockIdx.y][idx] = f2bf(v);
}

// ---------------------------------------------------------------------------
// LayerNorm over 512, fp32 in -> bf16 out. One wave per row.
// ---------------------------------------------------------------------------
__global__ __launch_bounds__(256)
void ln512(const float* __restrict__ X, const float* __restrict__ g,
           const float* __restrict__ bta, u16* __restrict__ out) {
    const int lane = threadIdx.x & 63, w = threadIdx.x >> 6;
    const long row = (long)blockIdx.x * 4 + w;
    const float* xp = X + row * 512 + lane * 8;
    f32x4 a = *(const f32x4*)xp;
    f32x4 c = *(const f32x4*)(xp + 4);
    float s = 0.f, ss = 0.f;
#pragma unroll
    for (int i = 0; i < 4; i++) { s += a[i] + c[i]; ss += a[i]*a[i] + c[i]*c[i]; }
#pragma unroll
    for (int m = 1; m < 64; m <<= 1) { s += __shfl_xor(s, m); ss += __shfl_xor(ss, m); }
    float mean = s * (1.f / 512.f);
    float var  = ss * (1.f / 512.f) - mean * mean;
    float rs = rsqrtf(var + 1e-5f);
    f32x4 g0 = *(const f32x4*)(g + lane * 8);
    f32x4 g1 = *(const f32x4*)(g + lane * 8 + 4);
    f32x4 b0 = *(const f32x4*)(bta + lane * 8);
    f32x4 b1 = *(const f32x4*)(bta + lane * 8 + 4);
    s16x8 ov;
#pragma unroll
    for (int i = 0; i < 4; i++) {
        ov[i]     = (short)f2bf((a[i] - mean) * rs * g0[i] + b0[i]);
        ov[4 + i] = (short)f2bf((c[i] - mean) * rs * g1[i] + b1[i]);
    }
    *(s16x8*)&out[row * 512 + lane * 8] = ov;
}

// LayerNorm over 100 (Zelta), out padded to 128 cols bf16 (pad = 0)
__global__ __launch_bounds__(256)
void ln_z(const float* __restrict__ Z, const float* __restrict__ g,
          const float* __restrict__ bta, u16* __restrict__ out) {
    const int lane = threadIdx.x & 63, w = threadIdx.x >> 6;
    const long row = (long)blockIdx.x * 4 + w;
    const float* zp = Z + row * 100;
    float x0 = zp[lane];
    float x1 = (lane < 36) ? zp[64 + lane] : 0.f;
    float s = x0 + x1, ss = x0 * x0 + x1 * x1;
#pragma unroll
    for (int m = 1; m < 64; m <<= 1) { s += __shfl_xor(s, m); ss += __shfl_xor(ss, m); }
    float mean = s * 0.01f;
    float var  = ss * 0.01f - mean * mean;
    float rs = rsqrtf(var + 1e-5f);
    out[row * 128 + lane] = f2bf((x0 - mean) * rs * g[lane] + bta[lane]);
    u16 hi = 0;
    if (lane < 36) hi = f2bf((x1 - mean) * rs * g[64 + lane] + bta[64 + lane]);
    out[row * 128 + 64 + lane] = hi;
}

// ---------------------------------------------------------------------------
// GEMM: C[M][N] = A[M][K](bf16) @ B (given as B^T bf16 [N][K]).
// Tile BM x BN, BK=32, 4 waves as 2x2 (wave tile BM/2 x BN/2).
// EPI 0: bf16 out. 1: bf16 gelu(acc+bias). 2: fp32 acc(+bias)+res.
// 3: bf16 acc*QSCALE (pre-scaled Q for attention exp2 path).
// ---------------------------------------------------------------------------
template <int BM, int BN, int EPI>
__global__ __launch_bounds__(256)
void gemm_t(const u16* __restrict__ A, const u16* __restrict__ BT,
            void* __restrict__ Outv, const float* __restrict__ bias,
            const float* __restrict__ res, int M, int N, int K) {
    __shared__ u16 Ash[BM * 32];
    __shared__ u16 Bsh[BN * 32];
    constexpr int MR = BM / 32;          // frags per wave in m
    constexpr int NR = BN / 32;          // frags per wave in n
    constexpr int ROUNDS = (BM + BN) / 64;
    const int tid = threadIdx.x;
    const int lane = tid & 63, w = tid >> 6;
    const int wm = w >> 1, wn = w & 1;
    const int lr = lane & 15, lg = lane >> 4;
    const int seg = lane & 3;
    const long m0 = (long)blockIdx.y * BM, n0 = (long)blockIdx.x * BN;

    f32x4 acc[MR][NR];
#pragma unroll
    for (int i = 0; i < MR; i++)
#pragma unroll
        for (int j = 0; j < NR; j++) { f32x4 z = {0.f, 0.f, 0.f, 0.f}; acc[i][j] = z; }

    const int ksteps = K >> 5;
    for (int kk = 0; kk < ksteps; ++kk) {
        const long k0 = (long)kk * 32;
        __syncthreads();  // previous tile's reads complete
#pragma unroll
        for (int rd = 0; rd < ROUNDS; rd++) {
            const int rbase = rd * 64 + w * 16;       // wave-uniform
            const int r = rbase + (lane >> 2);        // per-lane source row
            if (rbase < BM) {
                __builtin_amdgcn_global_load_lds(
                    (const __attribute__((address_space(1))) void*)(A + (m0 + r) * K + k0 + seg * 8),
                    (__attribute__((address_space(3))) void*)(&Ash[rbase * 32]), 16, 0, 0);
            } else {
                __builtin_amdgcn_global_load_lds(
                    (const __attribute__((address_space(1))) void*)(BT + (n0 + r - BM) * K + k0 + seg * 8),
                    (__attribute__((address_space(3))) void*)(&Bsh[(rbase - BM) * 32]), 16, 0, 0);
            }
        }
        __syncthreads();  // barrier drains vmcnt -> LDS tile ready
        s16x8 af[MR], bf[NR];
#pragma unroll
        for (int mi = 0; mi < MR; mi++)
            af[mi] = *(const s16x8*)&Ash[(wm * (BM / 2) + mi * 16 + lr) * 32 + lg * 8];
#pragma unroll
        for (int ni = 0; ni < NR; ni++)
            bf[ni] = *(const s16x8*)&Bsh[(wn * (BN / 2) + ni * 16 + lr) * 32 + lg * 8];
#pragma unroll
        for (int mi = 0; mi < MR; mi++)
#pragma unroll
            for (int ni = 0; ni < NR; ni++)
                acc[mi][ni] = __builtin_amdgcn_mfma_f32_16x16x32_bf16(af[mi], bf[ni], acc[mi][ni], 0, 0, 0);
    }
    // epilogue: D layout: m = 4*(lane>>4)+reg, n = lane&15
#pragma unroll
    for (int mi = 0; mi < MR; mi++) {
#pragma unroll
        for (int ni = 0; ni < NR; ni++) {
#pragma unroll
            for (int r = 0; r < 4; r++) {
                long gm = m0 + wm * (BM / 2) + mi * 16 + lg * 4 + r;
                long gn = n0 + wn * (BN / 2) + ni * 16 + lr;
                float v = acc[mi][ni][r];
                if constexpr (EPI == 1) {
                    v += bias[gn];
                    v = 0.5f * v * (1.f + erff(v * 0.70710678118654752f));
                }
                if constexpr (EPI == 2) {
                    if (bias) v += bias[gn];
                    v += res[gm * (long)N + gn];
                    ((float*)Outv)[gm * (long)N + gn] = v;
                } else if constexpr (EPI == 3) {
                    ((u16*)Outv)[gm * (long)N + gn] = f2bf(v * QSCALE);
                } else {
                    ((u16*)Outv)[gm * (long)N + gn] = f2bf(v);
                }
            }
        }
    }
}

// ---------------------------------------------------------------------------
// Gated flash attention v3. 8 heads, d=64. Q pre-scaled by 0.125*log2e;
// fixed-max softmax (scores bounded): p = 2^st, gate st>0; per-lane psum,
// one reduction at end. K/V fragments direct from L2 with register
// double-buffer. Block = 4 waves x 32 q-rows; BKV=32 per step (2 per iter).
// ---------------------------------------------------------------------------
__global__ __launch_bounds__(256)
void attn_gated3(const u16* __restrict__ Q, const u16* __restrict__ Kp,
                 const u16* __restrict__ VT, u16* __restrict__ O,
                 int Lq, int Lk, int Tk) {
    __shared__ u16 Psh[4][2][16 * 40];  // per-wave, per-subtile P bounce
    const int tid = threadIdx.x, lane = tid & 63, w = tid >> 6;
    const int lr = lane & 15, lg = lane >> 4;
    const int b = blockIdx.y >> 3, h = blockIdx.y & 7;
    const long qrow0 = (long)b * Lq + (long)blockIdx.x * 128 + w * 32;
    const long kbase = (long)b * Lk;
    const int hoff = h * 64;

    s16x8 qf[2][2];
#pragma unroll
    for (int s = 0; s < 2; s++)
#pragma unroll
        for (int dc = 0; dc < 2; dc++)
            qf[s][dc] = *(const s16x8*)&Q[(qrow0 + s * 16 + lr) * 512 + hoff + dc * 32 + lg * 8];

    f32x4 o[2][4];
#pragma unroll
    for (int s = 0; s < 2; s++)
#pragma unroll
        for (int dt = 0; dt < 4; dt++) { f32x4 z = {0.f, 0.f, 0.f, 0.f}; o[s][dt] = z; }
    float psum[2] = {0.f, 0.f};

    auto loadK = [&](s16x8 (&kf)[2][2], int kv0) {
#pragma unroll
        for (int c = 0; c < 2; c++)
#pragma unroll
            for (int dc = 0; dc < 2; dc++)
                kf[c][dc] = *(const s16x8*)&Kp[(kbase + kv0 + c * 16 + lr) * 512 + hoff + dc * 32 + lg * 8];
    };
    auto loadV = [&](s16x8 (&vb)[4], int kv0) {
#pragma unroll
        for (int dt = 0; dt < 4; dt++)
            vb[dt] = *(const s16x8*)&VT[(long)(hoff + dt * 16 + lr) * Tk + kbase + kv0 + lg * 8];
    };
    auto step = [&](const s16x8 (&kf)[2][2], const s16x8 (&vb)[4]) {
#pragma unroll
        for (int s = 0; s < 2; s++) {
            f32x4 st[2];
            { f32x4 z = {0.f, 0.f, 0.f, 0.f}; st[0] = z; st[1] = z; }
#pragma unroll
            for (int c = 0; c < 2; c++)
#pragma unroll
                for (int dc = 0; dc < 2; dc++)
                    st[c] = __builtin_amdgcn_mfma_f32_16x16x32_bf16(kf[c][dc], qf[s][dc], st[c], 0, 0, 0);
            // lane holds st = s*log2e for [k = kv0+c*16+4*lg+r][q = lr]
            uint2 pk[2];
#pragma unroll
            for (int c = 0; c < 2; c++) {
                float e0 = exp2f(st[c][0]), e1 = exp2f(st[c][1]);
                float e2 = exp2f(st[c][2]), e3 = exp2f(st[c][3]);
                psum[s] += (e0 + e1) + (e2 + e3);
                float g0 = st[c][0] > 0.f ? e0 : 0.f;
                float g1 = st[c][1] > 0.f ? e1 : 0.f;
                float g2 = st[c][2] > 0.f ? e2 : 0.f;
                float g3 = st[c][3] > 0.f ? e3 : 0.f;
                pk[c].x = pack_bf2(g0, g1);
                pk[c].y = pack_bf2(g2, g3);
            }
            u16* psh = &Psh[w][s][0];
#pragma unroll
            for (int c = 0; c < 2; c++)
                *(uint2*)&psh[lr * 40 + c * 16 + lg * 4] = pk[c];
            s16x8 pa = *(const s16x8*)&psh[lr * 40 + lg * 8];
#pragma unroll
            for (int dt = 0; dt < 4; dt++)
                o[s][dt] = __builtin_amdgcn_mfma_f32_16x16x32_bf16(pa, vb[dt], o[s][dt], 0, 0, 0);
        }
    };

    s16x8 kfA[2][2], vbA[4], kfB[2][2], vbB[4];
    loadK(kfA, 0); loadV(vbA, 0);
    for (int kv0 = 0; kv0 < Lk; kv0 += 64) {
        loadK(kfB, kv0 + 32); loadV(vbB, kv0 + 32);
        step(kfA, vbA);
        if (kv0 + 64 < Lk) { loadK(kfA, kv0 + 64); loadV(vbA, kv0 + 64); }
        step(kfB, vbB);
    }

#pragma unroll
    for (int s = 0; s < 2; s++) {
        float red = psum[s];
        red += __shfl_xor(red, 16);
        red += __shfl_xor(red, 32);
        float li0 = 1.f / __shfl(red, lg * 4 + 0), li1 = 1.f / __shfl(red, lg * 4 + 1);
        float li2 = 1.f / __shfl(red, lg * 4 + 2), li3 = 1.f / __shfl(red, lg * 4 + 3);
#pragma unroll
        for (int dt = 0; dt < 4; dt++) {
            long ob = (qrow0 + s * 16) * 512 + hoff + dt * 16 + lr;
            O[ob + (long)(lg * 4 + 0) * 512] = f2bf(o[s][dt][0] * li0);
            O[ob + (long)(lg * 4 + 1) * 512] = f2bf(o[s][dt][1] * li1);
            O[ob + (long)(lg * 4 + 2) * 512] = f2bf(o[s][dt][2] * li2);
            O[ob + (long)(lg * 4 + 3) * 512] = f2bf(o[s][dt][3] * li3);
        }
    }
}

// ---------------------------------------------------------------------------
extern "C" void kernel_launch(void* const* d_in, const int* in_sizes, int n_in,
                              void* d_out, int out_size, void* d_ws, size_t ws_size,
                              hipStream_t stream) {
    const float* X    = (const float*)d_in[0];   // [4,2048,512]
    const float* Z    = (const float*)d_in[1];   // [4,1024,100]
    const float* Wq_s = (const float*)d_in[2];
    const float* Wk_s = (const float*)d_in[3];
    const float* Wv_s = (const float*)d_in[4];
    const float* Wo_s = (const float*)d_in[5];
    const float* Wq_c = (const float*)d_in[6];
    const float* Wk_c = (const float*)d_in[7];   // [100,512]
    const float* Wv_c = (const float*)d_in[8];   // [100,512]
    const float* Wo_c = (const float*)d_in[9];
    const float* g1   = (const float*)d_in[10];
    const float* b1   = (const float*)d_in[11];
    const float* g2   = (const float*)d_in[12];
    const float* b2   = (const float*)d_in[13];
    const float* W1   = (const float*)d_in[14];
    const float* bf1  = (const float*)d_in[15];
    const float* W2   = (const float*)d_in[16];
    const float* bf2  = (const float*)d_in[17];
    float* out = (float*)d_out;

    char* p = (char*)d_ws;
    auto take = [&](size_t n) { char* q = p; p += (n + 255) & ~(size_t)255; return q; };
    u16* WqsT = (u16*)take(512 * 512 * 2);
    u16* WksT = (u16*)take(512 * 512 * 2);
    u16* WvsT = (u16*)take(512 * 512 * 2);
    u16* WosT = (u16*)take(512 * 512 * 2);
    u16* WqcT = (u16*)take(512 * 512 * 2);
    u16* WocT = (u16*)take(512 * 512 * 2);
    u16* W1T  = (u16*)take(512 * 512 * 2);
    u16* W2T  = (u16*)take(512 * 512 * 2);
    u16* WkcT = (u16*)take(512 * 128 * 2);
    u16* WvcT = (u16*)take(512 * 128 * 2);
    u16* nbuf = (u16*)take((size_t)8192 * 512 * 2);
    u16* qbuf = (u16*)take((size_t)8192 * 512 * 2);
    u16* kbuf = (u16*)take((size_t)8192 * 512 * 2);
    u16* vtbuf = (u16*)take((size_t)8192 * 512 * 2);  // V^T [512][tokens]
    u16* abuf = (u16*)take((size_t)8192 * 512 * 2);
    u16* znb  = (u16*)take((size_t)4096 * 128 * 2);

    // weights -> bf16 transposed (2 batched launches)
    WPtrs w8{};
    w8.s[0] = Wq_s; w8.d[0] = WqsT;
    w8.s[1] = Wk_s; w8.d[1] = WksT;
    w8.s[2] = Wv_s; w8.d[2] = WvsT;
    w8.s[3] = Wo_s; w8.d[3] = WosT;
    w8.s[4] = Wq_c; w8.d[4] = WqcT;
    w8.s[5] = Wo_c; w8.d[5] = WocT;
    w8.s[6] = W1;   w8.d[6] = W1T;
    w8.s[7] = W2;   w8.d[7] = W2T;
    wt_batch<<<dim3(1024, 8), 256, 0, stream>>>(w8, 512, 512, 512);
    WPtrs w2{};
    w2.s[0] = Wk_c; w2.d[0] = WkcT;
    w2.s[1] = Wv_c; w2.d[1] = WvcT;
    wt_batch<<<dim3(256, 2), 256, 0, stream>>>(w2, 100, 512, 128);

    // stage 1: self attention
    ln512<<<2048, 256, 0, stream>>>(X, g1, b1, nbuf);
    gemm_t<128, 64, 3><<<dim3(8, 64), 256, 0, stream>>>(nbuf, WqsT, qbuf, nullptr, nullptr, 8192, 512, 512);
    gemm_t<128, 64, 0><<<dim3(8, 64), 256, 0, stream>>>(nbuf, WksT, kbuf, nullptr, nullptr, 8192, 512, 512);
    // V transposed for free: vtbuf[n][m] = sum_k WvsT[n][k] * nbuf[m][k]
    gemm_t<64, 128, 0><<<dim3(64, 8), 256, 0, stream>>>(WvsT, nbuf, vtbuf, nullptr, nullptr, 512, 8192, 512);
    attn_gated3<<<dim3(16, 32), 256, 0, stream>>>(qbuf, kbuf, vtbuf, abuf, 2048, 2048, 8192);
    gemm_t<128, 64, 2><<<dim3(8, 64), 256, 0, stream>>>(abuf, WosT, d_out, nullptr, X, 8192, 512, 512);

    // stage 2: cross attention
    ln512<<<2048, 256, 0, stream>>>(out, g1, b1, nbuf);
    ln_z<<<1024, 256, 0, stream>>>(Z, g2, b2, znb);
    gemm_t<128, 64, 3><<<dim3(8, 64), 256, 0, stream>>>(nbuf, WqcT, qbuf, nullptr, nullptr, 8192, 512, 512);
    gemm_t<128, 64, 0><<<dim3(8, 32), 256, 0, stream>>>(znb, WkcT, kbuf, nullptr, nullptr, 4096, 512, 128);
    gemm_t<64, 128, 0><<<dim3(32, 8), 256, 0, stream>>>(WvcT, znb, vtbuf, nullptr, nullptr, 512, 4096, 128);
    attn_gated3<<<dim3(16, 32), 256, 0, stream>>>(qbuf, kbuf, vtbuf, abuf, 2048, 1024, 4096);
    gemm_t<128, 64, 2><<<dim3(8, 64), 256, 0, stream>>>(abuf, WocT, d_out, nullptr, out, 8192, 512, 512);

    // stage 3: FFN
    ln512<<<2048, 256, 0, stream>>>(out, g1, b1, nbuf);
    gemm_t<128, 64, 1><<<dim3(8, 64), 256, 0, stream>>>(nbuf, W1T, abuf, bf1, nullptr, 8192, 512, 512);
    gemm_t<128, 64, 2><<<dim3(8, 64), 256, 0, stream>>>(abuf, W2T, d_out, bf2, out, 8192, 512, 512);
}